// Round 12
// baseline (97.837 us; speedup 1.0000x reference)
//
#include <hip/hip_runtime.h>

typedef float f32x4 __attribute__((ext_vector_type(4)));
typedef __bf16 bf16x8 __attribute__((ext_vector_type(8)));
typedef unsigned short u16x8 __attribute__((ext_vector_type(8)));
typedef unsigned short u16x4 __attribute__((ext_vector_type(4)));

__device__ __forceinline__ unsigned short f2bf(float f) {
  union { float f; unsigned u; } v; v.f = f;
  unsigned r = v.u + 0x7FFFu + ((v.u >> 16) & 1u);
  return (unsigned short)(r >> 16);
}
__device__ __forceinline__ float bf2f(unsigned short u) {
  union { unsigned u; float f; } v; v.u = (unsigned)u << 16; return v.f;
}
// value is already an exact bf16 image -> truncation is exact
__device__ __forceinline__ unsigned short f2bf_exact(float f) {
  union { float f; unsigned u; } v; v.f = f;
  return (unsigned short)(v.u >> 16);
}
__device__ __forceinline__ u16x4 cvt4(f32x4 v) {   // HW RNE cvt (monotone)
  u16x4 o;
  o[0] = __builtin_bit_cast(unsigned short, (__bf16)v[0]);
  o[1] = __builtin_bit_cast(unsigned short, (__bf16)v[1]);
  o[2] = __builtin_bit_cast(unsigned short, (__bf16)v[2]);
  o[3] = __builtin_bit_cast(unsigned short, (__bf16)v[3]);
  return o;
}
__device__ __forceinline__ float min3f(float a, float b, float c) {
  return fminf(fminf(a, b), c);
}
__device__ __forceinline__ float max3f(float a, float b, float c) {
  return fmaxf(fmaxf(a, b), c);
}
__device__ __forceinline__ float med3f(float a, float b, float c) {
  return __builtin_amdgcn_fmed3f(a, b, c);
}

// conv_w fp32 [256][256] -> bf16 in MFMA-fragment-linear order:
// wbf[((ks*16 + ob)*64 + lane)*8 + j] = bf16(W[ob*16 + (lane&15)][ks*32 + (lane>>4)*8 + j])
__global__ void wconv_k(const float* __restrict__ w, unsigned short* __restrict__ wbf) {
  int idx  = blockIdx.x * 256 + threadIdx.x;   // 0..8191
  int lane = idx & 63;
  int ob   = (idx >> 6) & 15;
  int ks   = idx >> 10;                        // 0..7
  int o = (ob << 4) + (lane & 15);
  int c = (ks << 5) + ((lane >> 4) << 3);
  const float* src = w + (o << 8) + c;
  f32x4 v0 = *(const f32x4*)src;
  f32x4 v1 = *(const f32x4*)(src + 4);
  u16x8 ov;
  ov[0] = f2bf(v0[0]); ov[1] = f2bf(v0[1]); ov[2] = f2bf(v0[2]); ov[3] = f2bf(v0[3]);
  ov[4] = f2bf(v1[0]); ov[5] = f2bf(v1[1]); ov[6] = f2bf(v1[2]); ov[7] = f2bf(v1[3]);
  *(u16x8*)(wbf + (idx << 3)) = ov;
}

// One block = (batch, row-pair): 128 px x 256 oc. x staged as BF16 via
// reg-staging (T14: issue loads after barrier-1, cvt+ds_write after MFMA):
// median(bf16(x)) == bf16(median(x)) since RNE is monotone and median is an
// order statistic. Halves the dominant stage stream + Xs LDS. Residual
// folded from bf16 Xs. NT epilogue stores.
__launch_bounds__(256, 2)
__global__ void fused_k(const float* __restrict__ x,
                        const unsigned short* __restrict__ wbf,
                        const float* __restrict__ bias,
                        float* __restrict__ out) {
  __shared__ unsigned short Xs[128][64];   // 16 KB bf16: row = ci*4+dr, 8 granules x 8px, XOR-swizzled
  __shared__ unsigned short Bt[128][40];   // 10 KB med tile [px'][c-swizzled]

  const int t   = threadIdx.x;
  const int blk = blockIdx.x;
  const int swz = ((blk & 7) << 7) | (blk >> 3);   // XCD-bijective (1024 = 8*128)
  const int b   = swz >> 5;
  const int r0  = (swz & 31) << 1;         // rows r0, r0+1
  const int lane = t & 63;
  const int w    = t >> 6;
  const int g    = lane >> 4;
  const int l15  = lane & 15;

  // median task: channel ci = t>>3 (0..31, wave-private: ci>>3 == w), strip s = t&7
  const int ci  = t >> 3;
  const int s   = t & 7;
  const int px0 = s << 3;
  const int cw  = ci ^ ((s & 3) << 3);     // Bt bank-deconflict swizzle
  const bool hasL = (s > 0), hasR = (s < 7);
  const bool zTop = (r0 == 0), zBot = (r0 == 62);

  const float* xb = x + ((size_t)b << 20);

  float bn[4];
  #pragma unroll
  for (int n = 0; n < 4; ++n) bn[n] = bias[(w << 6) + (n << 4) + l15];

  // --- reg-staging addressing: issue p = channel cp=8w+p, rows dr=lane>>4 ---
  const int dr_st = lane >> 4;
  const int g16   = lane & 15;             // f32 granule (4 px)
  unsigned soff[8], wdst[8];
  #pragma unroll
  for (int p = 0; p < 8; ++p) {
    int cp = (w << 3) + p;
    int gr = r0 + dr_st - 1;
    gr = gr < 0 ? 0 : (gr > 63 ? 63 : gr);
    soff[p] = ((unsigned)cp << 14) + ((unsigned)gr << 8) + ((unsigned)g16 << 4);
    int gs = (g16 >> 1) ^ p ^ dr_st;       // 8px-granule XOR swizzle
    wdst[p] = (unsigned)(((cp << 2) + dr_st) << 6) + (unsigned)(gs << 3) + (unsigned)((g16 & 1) << 2);
  }
  unsigned short* XsF = &Xs[0][0];

  f32x4 ld[8];
  auto issue = [&](int step) {
    const unsigned kso = (unsigned)step << 19;
    #pragma unroll
    for (int p = 0; p < 8; ++p)
      ld[p] = *(const f32x4*)((const char*)xb + (soff[p] + kso));
  };
  auto commit = [&]() {
    #pragma unroll
    for (int p = 0; p < 8; ++p)
      *(u16x4*)&XsF[wdst[p]] = cvt4(ld[p]);
  };

  f32x4 acc[8][4];
  #pragma unroll
  for (int m = 0; m < 8; ++m)
    #pragma unroll
    for (int n = 0; n < 4; ++n)
      acc[m][n] = (f32x4){0.f, 0.f, 0.f, 0.f};

  // prologue
  issue(0); commit();
  __syncthreads();

  #pragma unroll
  for (int ks = 0; ks < 8; ++ks) {
    // --- W fragments (L2-hot) ---
    bf16x8 wfc[4];
    #pragma unroll
    for (int n = 0; n < 4; ++n) {
      const int fidx = (((ks << 4) + (w << 2) + n) << 6) + lane;
      wfc[n] = __builtin_bit_cast(bf16x8, *(const u16x8*)(wbf + ((size_t)fidx << 3)));
    }

    // --- median source reads: 4 rows x 8px bf16 (b128 each, phase-conflict-free) ---
    u16x8 xv[4];
    #pragma unroll
    for (int dr = 0; dr < 4; ++dr) {
      const int gs = s ^ (ci & 7) ^ dr;
      xv[dr] = *(const u16x8*)&XsF[(((ci << 2) + dr) << 6) + (gs << 3)];
    }

    // --- residual fold from bf16 Xs (steps 2w, 2w+1 only) ---
    if ((ks >> 1) == w) {
      const int h = ks & 1;
      #pragma unroll
      for (int nn = 0; nn < 2; ++nn) {
        const int n  = (h << 1) + nn;
        const int cx = (nn << 4) + l15;
        #pragma unroll
        for (int m = 0; m < 8; ++m) {
          const int dr = 1 + (m >> 2);
          const int gf = ((m & 3) << 1) + (g >> 1);
          const int gs = gf ^ (cx & 7) ^ dr;
          const u16x4 xv4 = *(const u16x4*)&XsF[(((cx << 2) + dr) << 6) + (gs << 3) + ((g & 1) << 2)];
          #pragma unroll
          for (int q = 0; q < 4; ++q) acc[m][n][q] += bf2f(xv4[q]);
        }
      }
    }

    // --- convert to f32 (exact) + halo shuffles ---
    float X[4][8];
    #pragma unroll
    for (int dr = 0; dr < 4; ++dr)
      #pragma unroll
      for (int j = 0; j < 8; ++j) X[dr][j] = bf2f(xv[dr][j]);
    float le[4], re[4];
    #pragma unroll
    for (int dr = 0; dr < 4; ++dr) {
      le[dr] = __shfl_up(X[dr][7], 1);
      re[dr] = __shfl_down(X[dr][0], 1);
    }

    // --- strip A (row r0): rows 0,1,2 ---
    {
      float R0[10], R1[10], R2[10];
      R0[0] = hasL ? le[0] : 0.f; R1[0] = hasL ? le[1] : 0.f; R2[0] = hasL ? le[2] : 0.f;
      R0[9] = hasR ? re[0] : 0.f; R1[9] = hasR ? re[1] : 0.f; R2[9] = hasR ? re[2] : 0.f;
      #pragma unroll
      for (int j = 0; j < 8; ++j) { R0[1 + j] = X[0][j]; R1[1 + j] = X[1][j]; R2[1 + j] = X[2][j]; }
      if (zTop) {
        #pragma unroll
        for (int j = 0; j < 10; ++j) R0[j] = 0.f;
      }
      float mn[10], md[10], mx[10];
      #pragma unroll
      for (int j = 0; j < 10; ++j) {
        mn[j] = min3f(R0[j], R1[j], R2[j]);
        md[j] = med3f(R0[j], R1[j], R2[j]);
        mx[j] = max3f(R0[j], R1[j], R2[j]);
      }
      #pragma unroll
      for (int i = 0; i < 8; ++i) {
        float t0 = max3f(mn[i], mn[i+1], mn[i+2]);
        float t1 = med3f(md[i], md[i+1], md[i+2]);
        float t2 = min3f(mx[i], mx[i+1], mx[i+2]);
        Bt[px0 + i][cw] = f2bf_exact(med3f(t0, t1, t2));
      }
    }
    // --- strip B (row r0+1): rows 1,2,3 ---
    {
      float R0[10], R1[10], R2[10];
      R0[0] = hasL ? le[1] : 0.f; R1[0] = hasL ? le[2] : 0.f; R2[0] = hasL ? le[3] : 0.f;
      R0[9] = hasR ? re[1] : 0.f; R1[9] = hasR ? re[2] : 0.f; R2[9] = hasR ? re[3] : 0.f;
      #pragma unroll
      for (int j = 0; j < 8; ++j) { R0[1 + j] = X[1][j]; R1[1 + j] = X[2][j]; R2[1 + j] = X[3][j]; }
      if (zBot) {
        #pragma unroll
        for (int j = 0; j < 10; ++j) R2[j] = 0.f;
      }
      float mn[10], md[10], mx[10];
      #pragma unroll
      for (int j = 0; j < 10; ++j) {
        mn[j] = min3f(R0[j], R1[j], R2[j]);
        md[j] = med3f(R0[j], R1[j], R2[j]);
        mx[j] = max3f(R0[j], R1[j], R2[j]);
      }
      #pragma unroll
      for (int i = 0; i < 8; ++i) {
        float t0 = max3f(mn[i], mn[i+1], mn[i+2]);
        float t1 = med3f(md[i], md[i+1], md[i+2]);
        float t2 = min3f(mx[i], mx[i+1], mx[i+2]);
        Bt[64 + px0 + i][cw] = f2bf_exact(med3f(t0, t1, t2));
      }
    }

    __syncthreads();   // [1] Bt published; all Xs reads drained

    if (ks < 7) issue(ks + 1);     // loads in flight across pa+MFMA
    __builtin_amdgcn_sched_barrier(0);

    // --- P fragments + MFMA ---
    bf16x8 pa[8];
    #pragma unroll
    for (int m = 0; m < 8; ++m) {
      const int px = (m << 4) + l15;
      const int gc = (g ^ ((px >> 3) & 3)) << 3;
      pa[m] = __builtin_bit_cast(bf16x8, *(const u16x8*)&Bt[px][gc]);
    }
    #pragma unroll
    for (int m = 0; m < 8; ++m)
      #pragma unroll
      for (int n = 0; n < 4; ++n)
        acc[m][n] = __builtin_amdgcn_mfma_f32_16x16x32_bf16(pa[m], wfc[n], acc[m][n], 0, 0, 0);

    if (ks < 7) commit();          // vmcnt wait here, then bf16 ds_writes

    __syncthreads();   // [2] Xs(ks+1) visible to all (fold is cross-wave)
  }

  // --- epilogue (write-only, non-temporal): px' = (m&3)*16+g*4+q, row r0+(m>>2) ---
  #pragma unroll
  for (int m = 0; m < 8; ++m) {
    #pragma unroll
    for (int n = 0; n < 4; ++n) {
      const int o = (w << 6) + (n << 4) + l15;
      const size_t idx = ((((size_t)b << 8) + (size_t)o) << 12)
                       + ((size_t)(r0 + (m >> 2)) << 6)
                       + (size_t)(((m & 3) << 4) + (g << 2));
      f32x4 res;
      #pragma unroll
      for (int q = 0; q < 4; ++q) res[q] = acc[m][n][q] + bn[n];
      __builtin_nontemporal_store(res, (f32x4*)(out + idx));
    }
  }
}

extern "C" void kernel_launch(void* const* d_in, const int* in_sizes, int n_in,
                              void* d_out, int out_size, void* d_ws, size_t ws_size,
                              hipStream_t stream) {
  const float* x  = (const float*)d_in[0];
  const float* cw = (const float*)d_in[1];
  const float* cb = (const float*)d_in[2];
  float* out = (float*)d_out;
  unsigned short* wbf = (unsigned short*)d_ws;   // 128 KB fragment-linear W

  hipLaunchKernelGGL(wconv_k, dim3(32), dim3(256), 0, stream, cw, wbf);
  hipLaunchKernelGGL(fused_k, dim3(1024), dim3(256), 0, stream, x, wbf, cb, out);
}

// Round 13
// 78.556 us; speedup vs baseline: 1.2454x; 1.2454x over previous
//
#include <hip/hip_runtime.h>

typedef float f32x4 __attribute__((ext_vector_type(4)));
typedef __bf16 bf16x8 __attribute__((ext_vector_type(8)));
typedef unsigned short u16x8 __attribute__((ext_vector_type(8)));

__device__ __forceinline__ unsigned short f2bf(float f) {
  union { float f; unsigned u; } v; v.f = f;
  unsigned r = v.u + 0x7FFFu + ((v.u >> 16) & 1u);
  return (unsigned short)(r >> 16);
}
__device__ __forceinline__ float min3f(float a, float b, float c) {
  return fminf(fminf(a, b), c);
}
__device__ __forceinline__ float max3f(float a, float b, float c) {
  return fmaxf(fmaxf(a, b), c);
}
__device__ __forceinline__ float med3f(float a, float b, float c) {
  return __builtin_amdgcn_fmed3f(a, b, c);
}

// async global->LDS, 16B per lane, LDS dest = wave-uniform base + lane*16
__device__ __forceinline__ void gload_lds16(const void* g, void* l) {
  __builtin_amdgcn_global_load_lds(
      (const __attribute__((address_space(1))) void*)g,
      (__attribute__((address_space(3))) void*)l, 16, 0, 0);
}

// conv_w fp32 [256][256] -> bf16 in MFMA-fragment-linear order:
// wbf[((ks*16 + ob)*64 + lane)*8 + j] = bf16(W[ob*16 + (lane&15)][ks*32 + (lane>>4)*8 + j])
__global__ void wconv_k(const float* __restrict__ w, unsigned short* __restrict__ wbf) {
  int idx  = blockIdx.x * 256 + threadIdx.x;   // 0..8191
  int lane = idx & 63;
  int ob   = (idx >> 6) & 15;
  int ks   = idx >> 10;                        // 0..7
  int o = (ob << 4) + (lane & 15);
  int c = (ks << 5) + ((lane >> 4) << 3);
  const float* src = w + (o << 8) + c;
  f32x4 v0 = *(const f32x4*)src;
  f32x4 v1 = *(const f32x4*)(src + 4);
  u16x8 ov;
  ov[0] = f2bf(v0[0]); ov[1] = f2bf(v0[1]); ov[2] = f2bf(v0[2]); ov[3] = f2bf(v0[3]);
  ov[4] = f2bf(v1[0]); ov[5] = f2bf(v1[1]); ov[6] = f2bf(v1[2]); ov[7] = f2bf(v1[3]);
  *(u16x8*)(wbf + (idx << 3)) = ov;
}

// One block = (batch, row-pair): 128 px x 256 oc. Xs is WAVE-PRIVATE
// (wave w stages+reads only channels 8w..8w+7; residual fold moved to the
// epilogue) and DOUBLE-BUFFERED. stage(ks+2) issued mid-step; VMEM queue
// [stage(ks+1), wf(ks), stage(ks+2)] makes the pre-MFMA wait vmcnt(8):
// drains stage(ks+1), keeps stage(ks+2) in flight ~1.2 steps. No vmcnt(0)
// in the loop; 2 raw s_barriers/step protect only Bt.
__launch_bounds__(256, 2)
__global__ void fused_k(const float* __restrict__ x,
                        const unsigned short* __restrict__ wbf,
                        const float* __restrict__ bias,
                        float* __restrict__ out) {
  __shared__ float Xs[2][128][64];         // 64 KB: row = ci*4+dr, px-granule swizzled
  __shared__ unsigned short Bt[128][40];   // 10 KB med tile [px'][c-swizzled]

  const int t   = threadIdx.x;
  const int blk = blockIdx.x;
  const int swz = ((blk & 7) << 7) | (blk >> 3);   // XCD-bijective (1024 = 8*128)
  const int b   = swz >> 5;
  const int r0  = (swz & 31) << 1;         // rows r0, r0+1
  const int lane = t & 63;
  const int w    = t >> 6;
  const int g    = lane >> 4;
  const int l15  = lane & 15;

  // median task: channel ci = t>>3 (wave-private: ci>>3 == w), strip s = t&7
  const int ci  = t >> 3;
  const int s   = t & 7;
  const int px0 = s << 3;
  const int cw  = ci ^ ((s & 3) << 3);     // Bt bank-deconflict swizzle
  const bool hasL = (s > 0), hasR = (s < 7);
  const bool zTop = (r0 == 0), zBot = (r0 == 62);

  const float* xb = x + ((size_t)b << 20);

  // bias first into the VMEM queue (drained by step-0 top wait)
  float bn[4];
  #pragma unroll
  for (int n = 0; n < 4; ++n) bn[n] = bias[(w << 6) + (n << 4) + l15];

  // staging: issue p stages channel cp=8w+p, rows dr=lane>>4 (4 rows = 1 KB)
  unsigned soff[8];
  #pragma unroll
  for (int p = 0; p < 8; ++p) {
    int cp = (w << 3) + p;
    int gr = r0 + (lane >> 4) - 1;
    gr = gr < 0 ? 0 : (gr > 63 ? 63 : gr);   // clamp; zeroed in VALU at median
    int bG = (lane & 15) ^ p;                // pre-swizzle px-granule by cp&7==p
    soff[p] = ((unsigned)cp << 14) + ((unsigned)gr << 8) + ((unsigned)bG << 4);
  }

  auto stage = [&](int step, int buf) {
    const unsigned kso = (unsigned)step << 19;   // step * 32ch * 16KB
    #pragma unroll
    for (int p = 0; p < 8; ++p)
      gload_lds16((const char*)xb + (soff[p] + kso), &Xs[buf][(w << 5) + (p << 2)][0]);
  };

  f32x4 acc[8][4];
  #pragma unroll
  for (int m = 0; m < 8; ++m)
    #pragma unroll
    for (int n = 0; n < 4; ++n)
      acc[m][n] = (f32x4){0.f, 0.f, 0.f, 0.f};

  // prologue: two tiles in flight
  stage(0, 0);
  stage(1, 1);

  const int ri0 = ci << 2;
  const int sig = ci & 7;
  const int bA  = ((s << 1)) ^ sig;
  const int bB  = ((s << 1) | 1) ^ sig;

  #pragma unroll
  for (int ks = 0; ks < 8; ++ks) {
    // (a) top wait: steady-state outstanding = stage(ks+1) [8] -> no-op.
    //     step 0: drains bias+stage(0), leaves stage(1).
    asm volatile("s_waitcnt vmcnt(8)" ::: "memory");
    __builtin_amdgcn_sched_barrier(0);

    // (b) median source reads from wave-private Xs[ks&1]: 4 rows x 2 vecs
    f32x4 va[4], vb[4];
    #pragma unroll
    for (int dr = 0; dr < 4; ++dr) {
      const float* rp = &Xs[ks & 1][ri0 + dr][0];
      va[dr] = *(const f32x4*)(rp + (bA << 2));
      vb[dr] = *(const f32x4*)(rp + (bB << 2));
    }
    // (b2) per-wave WAR fence: reads complete before stage(ks+2) targets
    //      this same buffer (data needed for compute anyway)
    asm volatile("s_waitcnt lgkmcnt(0)" ::: "memory");
    __builtin_amdgcn_sched_barrier(0);

    // (c1) W fragments for THIS step (older in queue than stage(ks+2))
    bf16x8 wfc[4];
    #pragma unroll
    for (int n = 0; n < 4; ++n) {
      const int fidx = (((ks << 4) + (w << 2) + n) << 6) + lane;
      wfc[n] = __builtin_bit_cast(bf16x8, *(const u16x8*)(wbf + ((size_t)fidx << 3)));
    }
    __builtin_amdgcn_sched_barrier(0);
    // (c2) stage(ks+2) into the buffer just consumed (wave-private, fenced)
    if (ks < 6) stage(ks + 2, ks & 1);
    __builtin_amdgcn_sched_barrier(0);

    // (d) median compute (halo via lane shuffles) + Bt stores
    {
      float le[4], re[4];
      #pragma unroll
      for (int dr = 0; dr < 4; ++dr) {
        le[dr] = __shfl_up(vb[dr][3], 1);
        re[dr] = __shfl_down(va[dr][0], 1);
      }
      // strip A (row r0): rows 0,1,2
      {
        float R0[10], R1[10], R2[10];
        R0[0] = hasL ? le[0] : 0.f; R1[0] = hasL ? le[1] : 0.f; R2[0] = hasL ? le[2] : 0.f;
        R0[9] = hasR ? re[0] : 0.f; R1[9] = hasR ? re[1] : 0.f; R2[9] = hasR ? re[2] : 0.f;
        #pragma unroll
        for (int j = 0; j < 4; ++j) {
          R0[1 + j] = va[0][j]; R0[5 + j] = vb[0][j];
          R1[1 + j] = va[1][j]; R1[5 + j] = vb[1][j];
          R2[1 + j] = va[2][j]; R2[5 + j] = vb[2][j];
        }
        if (zTop) {
          #pragma unroll
          for (int j = 0; j < 10; ++j) R0[j] = 0.f;
        }
        float mn[10], md[10], mx[10];
        #pragma unroll
        for (int j = 0; j < 10; ++j) {
          mn[j] = min3f(R0[j], R1[j], R2[j]);
          md[j] = med3f(R0[j], R1[j], R2[j]);
          mx[j] = max3f(R0[j], R1[j], R2[j]);
        }
        #pragma unroll
        for (int i = 0; i < 8; ++i) {
          float t0 = max3f(mn[i], mn[i+1], mn[i+2]);
          float t1 = med3f(md[i], md[i+1], md[i+2]);
          float t2 = min3f(mx[i], mx[i+1], mx[i+2]);
          Bt[px0 + i][cw] = f2bf(med3f(t0, t1, t2));
        }
      }
      // strip B (row r0+1): rows 1,2,3
      {
        float R0[10], R1[10], R2[10];
        R0[0] = hasL ? le[1] : 0.f; R1[0] = hasL ? le[2] : 0.f; R2[0] = hasL ? le[3] : 0.f;
        R0[9] = hasR ? re[1] : 0.f; R1[9] = hasR ? re[2] : 0.f; R2[9] = hasR ? re[3] : 0.f;
        #pragma unroll
        for (int j = 0; j < 4; ++j) {
          R0[1 + j] = va[1][j]; R0[5 + j] = vb[1][j];
          R1[1 + j] = va[2][j]; R1[5 + j] = vb[2][j];
          R2[1 + j] = va[3][j]; R2[5 + j] = vb[3][j];
        }
        if (zBot) {
          #pragma unroll
          for (int j = 0; j < 10; ++j) R2[j] = 0.f;
        }
        float mn[10], md[10], mx[10];
        #pragma unroll
        for (int j = 0; j < 10; ++j) {
          mn[j] = min3f(R0[j], R1[j], R2[j]);
          md[j] = med3f(R0[j], R1[j], R2[j]);
          mx[j] = max3f(R0[j], R1[j], R2[j]);
        }
        #pragma unroll
        for (int i = 0; i < 8; ++i) {
          float t0 = max3f(mn[i], mn[i+1], mn[i+2]);
          float t1 = med3f(md[i], md[i+1], md[i+2]);
          float t2 = min3f(mx[i], mx[i+1], mx[i+2]);
          Bt[64 + px0 + i][cw] = f2bf(med3f(t0, t1, t2));
        }
      }
    }

    // (e) publish Bt: LDS drain + raw barrier (NO vmcnt drain)
    asm volatile("s_waitcnt lgkmcnt(0)\n\ts_barrier" ::: "memory");
    __builtin_amdgcn_sched_barrier(0);

    // (f) P fragments (med tile, A-operand)
    bf16x8 pa[8];
    #pragma unroll
    for (int m = 0; m < 8; ++m) {
      const int px = (m << 4) + l15;
      const int gc = (g ^ ((px >> 3) & 3)) << 3;
      pa[m] = __builtin_bit_cast(bf16x8, *(const u16x8*)&Bt[px][gc]);
    }

    // (g) MFMA: compiler waits lgkm for pa and vmcnt(8) for wfc
    //     (drains stage(ks+1), keeps stage(ks+2) in flight)
    __builtin_amdgcn_s_setprio(1);
    #pragma unroll
    for (int m = 0; m < 8; ++m)
      #pragma unroll
      for (int n = 0; n < 4; ++n)
        acc[m][n] = __builtin_amdgcn_mfma_f32_16x16x32_bf16(pa[m], wfc[n], acc[m][n], 0, 0, 0);
    __builtin_amdgcn_s_setprio(0);

    // (h) all waves past their MFMA (pa reads drained) -> Bt reusable
    asm volatile("s_barrier" ::: "memory");
    __builtin_amdgcn_sched_barrier(0);
  }

  // --- epilogue: out = x + acc + bias (x re-read, L3-warm) ---
  // C layout: px' = (m&3)*16 + g*4 + q, row r0+(m>>2); oc = w*64+n*16+l15
  #pragma unroll
  for (int m = 0; m < 8; ++m) {
    #pragma unroll
    for (int n = 0; n < 4; ++n) {
      const int o = (w << 6) + (n << 4) + l15;
      const size_t idx = ((((size_t)b << 8) + (size_t)o) << 12)
                       + ((size_t)(r0 + (m >> 2)) << 6)
                       + (size_t)(((m & 3) << 4) + (g << 2));
      f32x4 xv = *(const f32x4*)(x + idx);
      f32x4 res;
      #pragma unroll
      for (int q = 0; q < 4; ++q) res[q] = xv[q] + acc[m][n][q] + bn[n];
      *(f32x4*)(out + idx) = res;
    }
  }
}

extern "C" void kernel_launch(void* const* d_in, const int* in_sizes, int n_in,
                              void* d_out, int out_size, void* d_ws, size_t ws_size,
                              hipStream_t stream) {
  const float* x  = (const float*)d_in[0];
  const float* cw = (const float*)d_in[1];
  const float* cb = (const float*)d_in[2];
  float* out = (float*)d_out;
  unsigned short* wbf = (unsigned short*)d_ws;   // 128 KB fragment-linear W

  hipLaunchKernelGGL(wconv_k, dim3(32), dim3(256), 0, stream, cw, wbf);
  hipLaunchKernelGGL(fused_k, dim3(1024), dim3(256), 0, stream, x, wbf, cb, out);
}

// Round 14
// 67.096 us; speedup vs baseline: 1.4582x; 1.1708x over previous
//
#include <hip/hip_runtime.h>

typedef float f32x4 __attribute__((ext_vector_type(4)));
typedef __bf16 bf16x8 __attribute__((ext_vector_type(8)));
typedef unsigned short u16x8 __attribute__((ext_vector_type(8)));

__device__ __forceinline__ unsigned short f2bf(float f) {
  union { float f; unsigned u; } v; v.f = f;
  unsigned r = v.u + 0x7FFFu + ((v.u >> 16) & 1u);
  return (unsigned short)(r >> 16);
}

__device__ __forceinline__ float min3f(float a, float b, float c) {
  return fminf(fminf(a, b), c);
}
__device__ __forceinline__ float max3f(float a, float b, float c) {
  return fmaxf(fmaxf(a, b), c);
}
__device__ __forceinline__ float med3f(float a, float b, float c) {
  return __builtin_amdgcn_fmed3f(a, b, c);
}

// async global->LDS, 16B per lane, LDS dest = wave-uniform base + lane*16
__device__ __forceinline__ void gload_lds16(const void* g, void* l) {
  __builtin_amdgcn_global_load_lds(
      (const __attribute__((address_space(1))) void*)g,
      (__attribute__((address_space(3))) void*)l, 16, 0, 0);
}

// conv_w fp32 [256][256] -> bf16 in MFMA-fragment-linear order:
// wbf[((ks*16 + ob)*64 + lane)*8 + j] = bf16(W[ob*16 + (lane&15)][ks*32 + (lane>>4)*8 + j])
__global__ void wconv_k(const float* __restrict__ w, unsigned short* __restrict__ wbf) {
  int idx  = blockIdx.x * 256 + threadIdx.x;   // 0..8191
  int lane = idx & 63;
  int ob   = (idx >> 6) & 15;
  int ks   = idx >> 10;                        // 0..7
  int o = (ob << 4) + (lane & 15);
  int c = (ks << 5) + ((lane >> 4) << 3);
  const float* src = w + (o << 8) + c;
  f32x4 v0 = *(const f32x4*)src;
  f32x4 v1 = *(const f32x4*)(src + 4);
  u16x8 ov;
  ov[0] = f2bf(v0[0]); ov[1] = f2bf(v0[1]); ov[2] = f2bf(v0[2]); ov[3] = f2bf(v0[3]);
  ov[4] = f2bf(v1[0]); ov[5] = f2bf(v1[1]); ov[6] = f2bf(v1[2]); ov[7] = f2bf(v1[3]);
  *(u16x8*)(wbf + (idx << 3)) = ov;
}

// One block = one (batch, row-PAIR): 128 output px x 256 oc. Stage 32ch x
// 4 rows per step (halo cost (R+2)/R = 2x), wf amortized over 128 px, and
// the residual x folded from the staged Xs tile (write-only epilogue).
// R6-style 2-barrier step. Epilogue stores are NON-TEMPORAL so the 128 MB
// out stream doesn't evict x from L2/L3 (x halo re-reads + graph replays).
__launch_bounds__(256, 2)
__global__ void fused_k(const float* __restrict__ x,
                        const unsigned short* __restrict__ wbf,
                        const float* __restrict__ bias,
                        float* __restrict__ out) {
  __shared__ float Xs[128][64];            // 32 KB: row = ci*4 + dr, px-block swizzled
  __shared__ unsigned short Bt[128][40];   // 10 KB: [px'][c-swizzled]

  const int t   = threadIdx.x;
  const int blk = blockIdx.x;
  const int swz = ((blk & 7) << 7) | (blk >> 3);   // XCD-bijective (1024 = 8*128)
  const int b   = swz >> 5;
  const int r0  = (swz & 31) << 1;         // even row, rows r0 and r0+1
  const int lane = t & 63;
  const int w    = t >> 6;       // wave 0..3
  const int g    = lane >> 4;    // lane group 0..3
  const int l15  = lane & 15;

  // median task: channel ci = t>>3 (0..31), strip s = t&7 (8 px, both rows)
  const int ci  = t >> 3;
  const int s   = t & 7;
  const int px0 = s << 3;
  const int cw  = ci ^ ((s & 3) << 3);     // Bt bank-deconflict swizzle
  const bool hasL = (s > 0), hasR = (s < 7);
  const bool zTop = (r0 == 0), zBot = (r0 == 62);

  const float* xb = x + ((size_t)b << 20);   // b * 256*64*64

  float bn[4];
  #pragma unroll
  for (int n = 0; n < 4; ++n) bn[n] = bias[(w << 6) + (n << 4) + l15];

  // staging: issue p stages channel cp=8w+p, rows dr=lane>>4 (4 rows = 1 KB)
  unsigned soff[8];
  #pragma unroll
  for (int p = 0; p < 8; ++p) {
    int cp = (w << 3) + p;
    int gr = r0 + (lane >> 4) - 1;
    gr = gr < 0 ? 0 : (gr > 63 ? 63 : gr);   // clamp; zeroed in VALU at median
    int bG = (lane & 15) ^ p;                // pre-swizzle px-block by cp&7==p
    soff[p] = ((unsigned)cp << 14) + ((unsigned)gr << 8) + ((unsigned)bG << 4);
  }

  auto stage = [&](int step) {
    const unsigned kso = (unsigned)step << 19;   // step * 32ch * 16KB
    #pragma unroll
    for (int p = 0; p < 8; ++p)
      gload_lds16((const char*)xb + (soff[p] + kso), &Xs[(w << 5) + (p << 2)][0]);
  };

  f32x4 acc[8][4];
  #pragma unroll
  for (int m = 0; m < 8; ++m)
    #pragma unroll
    for (int n = 0; n < 4; ++n)
      acc[m][n] = (f32x4){0.f, 0.f, 0.f, 0.f};

  stage(0);
  __syncthreads();

  const int ri0 = ci << 2;
  const int sig = ci & 7;
  const int bA  = ((s << 1)) ^ sig;
  const int bB  = ((s << 1) | 1) ^ sig;

  #pragma unroll
  for (int ks = 0; ks < 8; ++ks) {
    // --- W fragments (L2-hot, coalesced) ---
    bf16x8 wfc[4];
    #pragma unroll
    for (int n = 0; n < 4; ++n) {
      const int fidx = (((ks << 4) + (w << 2) + n) << 6) + lane;
      wfc[n] = __builtin_bit_cast(bf16x8, *(const u16x8*)(wbf + ((size_t)fidx << 3)));
    }

    // --- median source reads: 4 rows x 2 vecs ---
    f32x4 va[4], vb[4];
    #pragma unroll
    for (int dr = 0; dr < 4; ++dr) {
      const float* rp = &Xs[ri0 + dr][0];
      va[dr] = *(const f32x4*)(rp + (bA << 2));
      vb[dr] = *(const f32x4*)(rp + (bB << 2));
    }
    float le[4], re[4];
    #pragma unroll
    for (int dr = 0; dr < 4; ++dr) {
      le[dr] = __shfl_up(vb[dr][3], 1);
      re[dr] = __shfl_down(va[dr][0], 1);
    }

    // --- residual fold: at step ks = 2w+h, staged channels ARE wave w's
    //     out-channels for n in {2h, 2h+1}; rows r0,r0+1 = dr 1,2 ---
    if ((ks >> 1) == w) {
      const int h = ks & 1;
      #pragma unroll
      for (int nn = 0; nn < 2; ++nn) {
        const int n  = (h << 1) + nn;
        const int cx = (nn << 4) + l15;
        const int sx = cx & 7;
        const int rb = cx << 2;
        #pragma unroll
        for (int m = 0; m < 8; ++m) {
          const int bL = ((((m & 3) << 2) + g) ^ sx) << 2;
          const f32x4 xv = *(const f32x4*)&Xs[rb + 1 + (m >> 2)][bL];
          acc[m][n] += xv;
        }
      }
    }

    // --- strip A (output row r0): staged rows 0,1,2 ---
    {
      float R0[10], R1[10], R2[10];
      R0[0] = hasL ? le[0] : 0.f; R1[0] = hasL ? le[1] : 0.f; R2[0] = hasL ? le[2] : 0.f;
      R0[9] = hasR ? re[0] : 0.f; R1[9] = hasR ? re[1] : 0.f; R2[9] = hasR ? re[2] : 0.f;
      #pragma unroll
      for (int j = 0; j < 4; ++j) {
        R0[1 + j] = va[0][j]; R0[5 + j] = vb[0][j];
        R1[1 + j] = va[1][j]; R1[5 + j] = vb[1][j];
        R2[1 + j] = va[2][j]; R2[5 + j] = vb[2][j];
      }
      if (zTop) {
        #pragma unroll
        for (int j = 0; j < 10; ++j) R0[j] = 0.f;
      }
      float mn[10], md[10], mx[10];
      #pragma unroll
      for (int j = 0; j < 10; ++j) {
        mn[j] = min3f(R0[j], R1[j], R2[j]);
        md[j] = med3f(R0[j], R1[j], R2[j]);
        mx[j] = max3f(R0[j], R1[j], R2[j]);
      }
      #pragma unroll
      for (int i = 0; i < 8; ++i) {
        float t0 = max3f(mn[i], mn[i+1], mn[i+2]);
        float t1 = med3f(md[i], md[i+1], md[i+2]);
        float t2 = min3f(mx[i], mx[i+1], mx[i+2]);
        Bt[px0 + i][cw] = f2bf(med3f(t0, t1, t2));
      }
    }
    // --- strip B (output row r0+1): staged rows 1,2,3 ---
    {
      float R0[10], R1[10], R2[10];
      R0[0] = hasL ? le[1] : 0.f; R1[0] = hasL ? le[2] : 0.f; R2[0] = hasL ? le[3] : 0.f;
      R0[9] = hasR ? re[1] : 0.f; R1[9] = hasR ? re[2] : 0.f; R2[9] = hasR ? re[3] : 0.f;
      #pragma unroll
      for (int j = 0; j < 4; ++j) {
        R0[1 + j] = va[1][j]; R0[5 + j] = vb[1][j];
        R1[1 + j] = va[2][j]; R1[5 + j] = vb[2][j];
        R2[1 + j] = va[3][j]; R2[5 + j] = vb[3][j];
      }
      if (zBot) {
        #pragma unroll
        for (int j = 0; j < 10; ++j) R2[j] = 0.f;
      }
      float mn[10], md[10], mx[10];
      #pragma unroll
      for (int j = 0; j < 10; ++j) {
        mn[j] = min3f(R0[j], R1[j], R2[j]);
        md[j] = med3f(R0[j], R1[j], R2[j]);
        mx[j] = max3f(R0[j], R1[j], R2[j]);
      }
      #pragma unroll
      for (int i = 0; i < 8; ++i) {
        float t0 = max3f(mn[i], mn[i+1], mn[i+2]);
        float t1 = med3f(md[i], md[i+1], md[i+2]);
        float t2 = min3f(mx[i], mx[i+1], mx[i+2]);
        Bt[64 + px0 + i][cw] = f2bf(med3f(t0, t1, t2));
      }
    }

    __syncthreads();   // publish Bt; Xs reads complete (lgkm drained)

    if (ks < 7) stage(ks + 1);   // overwrite Xs (safe), drains at next barrier

    // --- P fragments + MFMA: px' = m*16+l15 (m 0..7), oc = w*64+n*16+l15 ---
    bf16x8 pa[8];
    #pragma unroll
    for (int m = 0; m < 8; ++m) {
      const int px = (m << 4) + l15;
      const int gc = (g ^ ((px >> 3) & 3)) << 3;
      pa[m] = __builtin_bit_cast(bf16x8, *(const u16x8*)&Bt[px][gc]);
    }
    #pragma unroll
    for (int m = 0; m < 8; ++m)
      #pragma unroll
      for (int n = 0; n < 4; ++n)
        acc[m][n] = __builtin_amdgcn_mfma_f32_16x16x32_bf16(pa[m], wfc[n], acc[m][n], 0, 0, 0);

    if (ks < 7) __syncthreads();   // stage landed + Bt consumed
  }

  // --- epilogue (write-only, NON-TEMPORAL): px' = (m&3)*16+g*4+q, row r0+(m>>2) ---
  #pragma unroll
  for (int m = 0; m < 8; ++m) {
    #pragma unroll
    for (int n = 0; n < 4; ++n) {
      const int o = (w << 6) + (n << 4) + l15;
      const size_t idx = ((((size_t)b << 8) + (size_t)o) << 12)
                       + ((size_t)(r0 + (m >> 2)) << 6)
                       + (size_t)(((m & 3) << 4) + (g << 2));
      f32x4 res;
      #pragma unroll
      for (int q = 0; q < 4; ++q) res[q] = acc[m][n][q] + bn[n];
      __builtin_nontemporal_store(res, (f32x4*)(out + idx));
    }
  }
}

extern "C" void kernel_launch(void* const* d_in, const int* in_sizes, int n_in,
                              void* d_out, int out_size, void* d_ws, size_t ws_size,
                              hipStream_t stream) {
  const float* x  = (const float*)d_in[0];
  const float* cw = (const float*)d_in[1];
  const float* cb = (const float*)d_in[2];
  float* out = (float*)d_out;
  unsigned short* wbf = (unsigned short*)d_ws;   // 128 KB fragment-linear W

  hipLaunchKernelGGL(wconv_k, dim3(32), dim3(256), 0, stream, cw, wbf);
  hipLaunchKernelGGL(fused_k, dim3(1024), dim3(256), 0, stream, x, wbf, cb, out);
}